// Round 14
// baseline (8151.653 us; speedup 1.0000x reference)
//
#include <hip/hip_runtime.h>

typedef float f4 __attribute__((ext_vector_type(4)));

#define NT 256
#define BB 128
#define BT 100
#define DZc 64
#define DAc 32
#define DUc 8
#define KMIX 8
#define DOBSc 16
#define HG 128
#define DINc 56   // DA + DOBS + DU

// flat element offsets into d_out (return order of the reference tuple)
#define O_ZFILT   0LL
#define O_PFILT   819200LL
#define O_ZPRED   53248000LL
#define O_AFILT   54067200LL
#define O_APRED   54476800LL
#define O_PPRED   54886400LL
#define O_ALPHA   107315200LL
#define O_ASEQ    107417600LL
#define O_BSEQ    159846400LL
#define O_CSEQ    166400000LL
#define O_ZMEAN   192614400LL
#define O_LTRIL   193433600LL
#define O_SPRED   245862400LL

__device__ __forceinline__ float dot4(f4 a, f4 b) {
    return a[0]*b[0] + a[1]*b[1] + a[2]*b[2] + a[3]*b[3];
}

struct SMem {
    float P[DZc][68];     // covariance carry (P_pred -> P_filt -> P_pred)
    float A[DZc][68];     // mixed A (row-major)
    float AT[DZc][65];    // A transposed (2-way write pattern, free)
    float Wk[DZc][68];    // temp: A @ P_filt
    float Qm[DZc][68];    // Q cached
    float C[DAc][68];     // mixed C
    float CP[DAc][68];    // C@P
    float Xm[DAc][68];    // X = S^{-1} C P
    float S[DAc][33];     // innovation cov -> L (raw cols) after shfl-LDL writeback
    float Rm[DAc][33];    // R cached
    float dinv[DAc];
    float Bm[DZc][8];     // mixed B
    float z[DZc], zp[DZc], zn[DZc];
    float h[HG], hn[HG];
    float gh[3*HG], gi[3*HG];   // only used by init + !mk1 slow path
    float x[64];          // [a_k_hat(32) | h_obs(16) | u(8)]
    float ak[DAc], rvec[DAc];
    float akN[DAc];       // prefetched a(t+1)
    float ubuf[2][8];     // u double-buffer: ubuf[t&1] = u(t)
    float mkN;            // prefetched mask(t+1)
    float lg[8];
    float mk;
};

template<bool EMIT>
__device__ __forceinline__ void mix_apply(SMem& s, int tid, size_t bt, const float* al8,
    const float* __restrict__ A_mats, const float* __restrict__ B_mats,
    const float* __restrict__ C_mats, float* __restrict__ out)
{
    const f4* A4 = (const f4*)A_mats;
    const f4* B4 = (const f4*)B_mats;
    const f4* C4 = (const f4*)C_mats;
    #pragma unroll 2
    for (int e = 0; e < 4; ++e) {
        int i4 = tid + e*256;
        f4 acc = {0.f,0.f,0.f,0.f};
        #pragma unroll
        for (int k = 0; k < 8; ++k) acc += al8[k] * A4[k*1024 + i4];
        int row = i4 >> 4, cb = (i4 & 15) * 4;
        *(f4*)&s.A[row][cb] = acc;
        s.AT[cb][row] = acc[0]; s.AT[cb+1][row] = acc[1];
        s.AT[cb+2][row] = acc[2]; s.AT[cb+3][row] = acc[3];
        if (EMIT) *(f4*)&out[O_ASEQ + bt*4096 + (size_t)i4*4] = acc;
    }
    if (tid < 128) {
        int i4 = tid;
        f4 acc = {0.f,0.f,0.f,0.f};
        #pragma unroll
        for (int k = 0; k < 8; ++k) acc += al8[k] * B4[k*128 + i4];
        *(f4*)&s.Bm[i4>>1][(i4&1)*4] = acc;
        if (EMIT) *(f4*)&out[O_BSEQ + bt*512 + (size_t)i4*4] = acc;
    }
    #pragma unroll 1
    for (int e = 0; e < 2; ++e) {
        int i4 = tid + e*256;
        f4 acc = {0.f,0.f,0.f,0.f};
        #pragma unroll
        for (int k = 0; k < 8; ++k) acc += al8[k] * C4[k*512 + i4];
        *(f4*)&s.C[i4>>4][(i4&15)*4] = acc;
    }
}

__global__ void __launch_bounds__(NT, 1)
kalman_seq(const float* __restrict__ a_seq, const float* __restrict__ h_obs,
           const float* __restrict__ u_seq, const float* __restrict__ mask,
           const float* __restrict__ A_mats, const float* __restrict__ B_mats,
           const float* __restrict__ C_mats, const float* __restrict__ a_0,
           const float* __restrict__ P_0, const float* __restrict__ Q,
           const float* __restrict__ R, const float* __restrict__ W_ih,
           const float* __restrict__ W_hh, const float* __restrict__ b_ih,
           const float* __restrict__ b_hh, const float* __restrict__ W_out,
           const float* __restrict__ b_out, float* __restrict__ out)
{
    __shared__ SMem s;
    const int b = blockIdx.x;
    const int tid = threadIdx.x;
    const int r4 = (tid >> 4) << 2;   // 4-row base
    const int c4 = (tid & 15) << 2;   // 4-col base

    // ---------------- init ----------------
    for (int idx = tid; idx < DZc*DZc; idx += NT) {
        s.P[idx >> 6][idx & 63]  = P_0[idx];
        s.Qm[idx >> 6][idx & 63] = Q[idx];
    }
    for (int idx = tid; idx < DAc*DAc; idx += NT) s.Rm[idx >> 5][idx & 31] = R[idx];
    if (tid < HG) s.h[tid] = 0.f;
    if (tid < DZc) { s.z[tid] = 0.f; s.zp[tid] = 0.f; }
    if (tid < DAc)                 s.x[tid] = a_0[tid];
    else if (tid < DAc + DOBSc)    s.x[tid] = h_obs[b*DOBSc + (tid - DAc)];
    else if (tid < DINc)           s.x[tid] = u_seq[(size_t)b*BT*DUc + (tid - DAc - DOBSc)];
    // prefill step-0 "prefetched" inputs
    if (tid >= 128 && tid < 160)      s.akN[tid-128] = a_seq[(size_t)b*BT*DAc + (tid-128)];
    else if (tid >= 160 && tid < 168) { s.ubuf[0][tid-160] = u_seq[(size_t)b*BT*DUc + (tid-160)];
                                        s.ubuf[1][tid-160] = 0.f; }
    else if (tid == 168)              s.mkN = mask[(size_t)b*BT];
    __syncthreads();

    // init alpha_net (h = 0 -> gh = b_hh exactly)
    for (int g = tid; g < 3*HG; g += NT) {
        const float* wi = W_ih + (size_t)g * DINc;
        f4 ai = {0.f,0.f,0.f,0.f};
        #pragma unroll 7
        for (int q = 0; q < 14; ++q) ai += *(const f4*)(wi + q*4) * *(const f4*)&s.x[q*4];
        s.gi[g] = ai[0]+ai[1]+ai[2]+ai[3] + b_ih[g];
        s.gh[g] = b_hh[g];
    }
    __syncthreads();
    if (tid < HG) {
        float r  = 1.f / (1.f + expf(-(s.gi[tid] + s.gh[tid])));
        float zg = 1.f / (1.f + expf(-(s.gi[HG+tid] + s.gh[HG+tid])));
        float n  = tanhf(s.gi[2*HG+tid] + r * s.gh[2*HG+tid]);
        s.h[tid] = (1.f - zg) * n;    // h_old = 0
    }
    __syncthreads();
    if (tid < KMIX) {
        const float* wo = W_out + tid * HG;
        f4 acc = {0.f,0.f,0.f,0.f};
        #pragma unroll 8
        for (int q = 0; q < 32; ++q) acc += *(const f4*)(wo + q*4) * *(const f4*)&s.h[q*4];
        s.lg[tid] = acc[0]+acc[1]+acc[2]+acc[3] + b_out[tid];
    }
    __syncthreads();
    {
        float lg[8];
        #pragma unroll
        for (int k = 0; k < 8; ++k) lg[k] = s.lg[k];
        float mx = lg[0];
        #pragma unroll
        for (int k = 1; k < 8; ++k) mx = fmaxf(mx, lg[k]);
        float al[8]; float sum = 0.f;
        #pragma unroll
        for (int k = 0; k < 8; ++k) { al[k] = expf(lg[k] - mx); sum += al[k]; }
        float rs = 1.f / sum;
        #pragma unroll
        for (int k = 0; k < 8; ++k) al[k] *= rs;
        mix_apply<false>(s, tid, 0, al, A_mats, B_mats, C_mats, out);
    }
    __syncthreads();

    for (int t = 0; t < BT; ++t) {
        const size_t bt = (size_t)b * BT + t;
        const int cur = t & 1;

        // ---- P0 (cheap): zp += B (u_new - u_old) ; publish prefetched inputs ----
        if (tid < 64) {
            float acc = s.zp[tid];
            #pragma unroll
            for (int q = 0; q < DUc; ++q)
                acc += s.Bm[tid][q] * (s.ubuf[cur][q] - s.ubuf[cur^1][q]);
            s.zp[tid] = acc;
        } else if (tid < 96) {
            float av = s.akN[tid-64];
            s.ak[tid-64] = av;
            s.x[tid-64] = av;                 // speculative a_k_hat (exact when mk==1)
        } else if (tid < 104) {
            s.x[48 + (tid-96)] = s.ubuf[cur][tid-96];
        } else if (tid == 104) {
            s.mk = s.mkN;
        }
        __syncthreads();
        const float mkv = s.mk;
        const bool mk1 = (mkv == 1.0f);

        // ---- P1: CP = C @ P (1 row x 8 cols per thread) ; rvec ----
        {
            const int r = tid >> 3;
            const int c8 = (tid & 7) * 8;
            f4 acc0 = {0.f,0.f,0.f,0.f}, acc1 = {0.f,0.f,0.f,0.f};
            #pragma unroll 4
            for (int k4 = 0; k4 < 16; ++k4) {
                f4 cr = *(const f4*)&s.C[r][k4*4];
                #pragma unroll
                for (int kk = 0; kk < 4; ++kk) {
                    float cv = cr[kk];
                    acc0 += cv * *(const f4*)&s.P[k4*4+kk][c8];
                    acc1 += cv * *(const f4*)&s.P[k4*4+kk][c8+4];
                }
            }
            *(f4*)&s.CP[r][c8]   = acc0;
            *(f4*)&s.CP[r][c8+4] = acc1;
        }
        if (tid < DAc) {
            float acc = 0.f;
            #pragma unroll 4
            for (int k4 = 0; k4 < 16; ++k4)
                acc += dot4(*(const f4*)&s.C[tid][k4*4], *(const f4*)&s.zp[k4*4]);
            s.rvec[tid] = s.ak[tid] - acc;
        }
        __syncthreads();

        // ---- P2: S = CP C^T + R (1x4 tiles) ; coalesced f4 emit ----
        {
            const int r = tid >> 3;
            const int cb = (tid & 7) * 4;
            f4 acc = {0.f,0.f,0.f,0.f};
            #pragma unroll 4
            for (int k4 = 0; k4 < 16; ++k4) {
                f4 a = *(const f4*)&s.CP[r][k4*4];
                #pragma unroll
                for (int j = 0; j < 4; ++j)
                    acc[j] += dot4(a, *(const f4*)&s.C[cb+j][k4*4]);
            }
            f4 rm = {s.Rm[r][cb], s.Rm[r][cb+1], s.Rm[r][cb+2], s.Rm[r][cb+3]};
            f4 v = acc + rm;
            s.S[r][cb] = v[0]; s.S[r][cb+1] = v[1]; s.S[r][cb+2] = v[2]; s.S[r][cb+3] = v[3];
            *(f4*)&out[O_SPRED + bt*1024 + (size_t)r*32 + cb] = v;
        }
        __syncthreads();

        // ---- P3: wave0: SHFL-LDL (zero fences) + reg solves + zn + a_filt
        //          waves1-2: GRU gates fully in-register -> s.hn
        //          wave3: C_seq emit ----
        if (tid < 64) {
            const int lane = tid;
            const int l = lane & 31;
            float row[32];
            #pragma unroll
            for (int j = 0; j < 32; ++j) row[j] = s.S[l][j];
            // shfl-LDL: S[j][k] = __shfl(row[k], j) — static register index, no LDS
            #pragma unroll
            for (int k = 0; k < 32; ++k) {
                float piv = __shfl(row[k], k);
                float dv = 1.0f / piv;
                if (lane == k) s.dinv[k] = dv;
                float fm = (l > k) ? (row[k] * dv) : 0.f;
                #pragma unroll
                for (int j = k+1; j < 32; ++j)
                    row[j] -= fm * __shfl(row[k], j);
            }
            if (lane < 32) {
                #pragma unroll
                for (int j = 0; j < 32; ++j) s.S[l][j] = row[j];
            }
            __threadfence_block();
            // Solve S x = CP[:, lane] via L D L^T — registers, broadcast LDS reads
            float v[32];
            #pragma unroll
            for (int r = 0; r < 32; ++r) v[r] = s.CP[r][lane];
            #pragma unroll
            for (int r = 0; r < 32; ++r) {
                float acc = v[r];
                #pragma unroll
                for (int k = 0; k < r; ++k) acc -= s.S[r][k] * v[k];
                v[r] = s.dinv[r] * acc;
            }
            #pragma unroll
            for (int r = 30; r >= 0; --r) {
                float acc = 0.f;
                #pragma unroll
                for (int k = r+1; k < 32; ++k) acc += s.S[k][r] * v[k];
                v[r] -= s.dinv[r] * acc;
            }
            float accz = 0.f;
            #pragma unroll
            for (int r = 0; r < 32; ++r) {
                s.Xm[r][lane] = v[r];
                accz += v[r] * s.rvec[r];
            }
            s.zn[lane] = s.zp[lane] + mkv * accz;
            __threadfence_block();
            if (lane < DAc) {
                float acc = 0.f;
                #pragma unroll 4
                for (int k4 = 0; k4 < 16; ++k4)
                    acc += dot4(*(const f4*)&s.C[lane][k4*4], *(const f4*)&s.zn[k4*4]);
                out[O_AFILT + bt*DAc + lane] = acc;
                if (!mk1) s.x[lane] = mkv * s.ak[lane] + (1.f - mkv) * acc;
            }
        } else if (tid < 192) {
            const int idx = tid - 64;                // 0..127
            const float* wir = W_ih + (size_t)idx * DINc;
            const float* wiz = W_ih + (size_t)(HG + idx) * DINc;
            const float* win = W_ih + (size_t)(2*HG + idx) * DINc;
            const float* whr = W_hh + (size_t)idx * HG;
            const float* whz = W_hh + (size_t)(HG + idx) * HG;
            const float* whn = W_hh + (size_t)(2*HG + idx) * HG;
            f4 air = {0.f,0.f,0.f,0.f}, aiz = {0.f,0.f,0.f,0.f}, ain = {0.f,0.f,0.f,0.f};
            #pragma unroll 4
            for (int q = 0; q < 14; ++q) {
                f4 xv = *(const f4*)&s.x[q*4];
                air += *(const f4*)(wir + q*4) * xv;
                aiz += *(const f4*)(wiz + q*4) * xv;
                ain += *(const f4*)(win + q*4) * xv;
            }
            f4 ahr = {0.f,0.f,0.f,0.f}, ahz = {0.f,0.f,0.f,0.f}, ahn = {0.f,0.f,0.f,0.f};
            #pragma unroll 4
            for (int q = 0; q < 32; ++q) {
                f4 hv = *(const f4*)&s.h[q*4];
                ahr += *(const f4*)(whr + q*4) * hv;
                ahz += *(const f4*)(whz + q*4) * hv;
                ahn += *(const f4*)(whn + q*4) * hv;
            }
            float gir = air[0]+air[1]+air[2]+air[3] + b_ih[idx];
            float giz = aiz[0]+aiz[1]+aiz[2]+aiz[3] + b_ih[HG + idx];
            float gin = ain[0]+ain[1]+ain[2]+ain[3] + b_ih[2*HG + idx];
            float ghr = ahr[0]+ahr[1]+ahr[2]+ahr[3] + b_hh[idx];
            float ghz = ahz[0]+ahz[1]+ahz[2]+ahz[3] + b_hh[HG + idx];
            float ghn = ahn[0]+ahn[1]+ahn[2]+ahn[3] + b_hh[2*HG + idx];
            float r  = 1.f / (1.f + expf(-(gir + ghr)));
            float zg = 1.f / (1.f + expf(-(giz + ghz)));
            float n  = tanhf(gin + r * ghn);
            s.hn[idx] = (1.f - zg) * n + zg * s.h[idx];
        } else {
            const int l = tid - 192;
            #pragma unroll 2
            for (int e = 0; e < 8; ++e) {
                int i4 = l + e*64;
                *(f4*)&out[O_CSEQ + bt*2048 + (size_t)i4*4] = *(const f4*)&s.C[i4>>4][(i4&15)*4];
            }
        }
        __syncthreads();

        // ---- prefetch next-step inputs (issue now, store at P8 end) ----
        float pfA = 0.f, pfU = 0.f, pfM = 0.f;
        {
            const int t2 = (t+1 < BT) ? (t+1) : t;
            const size_t bt2 = (size_t)b*BT + t2;
            if (tid >= 192 && tid < 224)      pfA = a_seq[bt2*DAc + (tid-192)];
            else if (tid >= 224 && tid < 232) pfU = u_seq[bt2*DUc + (tid-224)];
            else if (tid == 232)              pfM = mask[bt2];
        }

        // ---- P4: P_filt fused update + emits ; (slow path if !mk1) ;
        //          logits + softmax + mix + h<-hn ----
        {
            const float coef = (mkv*mkv - 2.f*mkv) * 0.5f;
            f4 acc0 = {0.f,0.f,0.f,0.f}, acc1 = {0.f,0.f,0.f,0.f};
            f4 acc2 = {0.f,0.f,0.f,0.f}, acc3 = {0.f,0.f,0.f,0.f};
            #pragma unroll 4
            for (int l = 0; l < DAc; ++l) {
                f4 cpc = *(const f4*)&s.CP[l][c4];
                f4 xc  = *(const f4*)&s.Xm[l][c4];
                f4 cpr = *(const f4*)&s.CP[l][r4];
                f4 xr  = *(const f4*)&s.Xm[l][r4];
                acc0 += xr[0]*cpc + cpr[0]*xc;
                acc1 += xr[1]*cpc + cpr[1]*xc;
                acc2 += xr[2]*cpc + cpr[2]*xc;
                acc3 += xr[3]*cpc + cpr[3]*xc;
            }
            #pragma unroll
            for (int i = 0; i < 4; ++i) {
                const int row = r4 + i;
                f4 g = (i==0) ? acc0 : (i==1) ? acc1 : (i==2) ? acc2 : acc3;
                f4 p = *(const f4*)&s.P[row][c4];
                f4 v = p + coef * g;
                *(f4*)&s.P[row][c4] = v;
                *(f4*)&out[O_PFILT + bt*4096 + (size_t)row*64 + c4] = v;
            }
        }
        if (tid < DZc) {
            float v = s.zn[tid];
            out[O_ZFILT + bt*DZc + tid] = v;
            out[O_ZMEAN + bt*DZc + tid] = v;
            s.z[tid] = v;
        }

        if (!mk1) {
            __syncthreads();
            for (int g = tid; g < 3*HG; g += NT) {
                const float* wi = W_ih + (size_t)g * DINc;
                const float* wh = W_hh + (size_t)g * HG;
                f4 ai = {0.f,0.f,0.f,0.f}, ah = {0.f,0.f,0.f,0.f};
                #pragma unroll 7
                for (int q = 0; q < 14; ++q) ai += *(const f4*)(wi + q*4) * *(const f4*)&s.x[q*4];
                #pragma unroll 8
                for (int q = 0; q < 32; ++q) ah += *(const f4*)(wh + q*4) * *(const f4*)&s.h[q*4];
                s.gi[g] = ai[0]+ai[1]+ai[2]+ai[3] + b_ih[g];
                s.gh[g] = ah[0]+ah[1]+ah[2]+ah[3] + b_hh[g];
            }
            __syncthreads();
            if (tid < HG) {
                float gi0 = s.gi[tid], gi1 = s.gi[HG+tid], gi2 = s.gi[2*HG+tid];
                float gh0 = s.gh[tid], gh1 = s.gh[HG+tid], gh2 = s.gh[2*HG+tid];
                float hold = s.h[tid];
                float r  = 1.f / (1.f + expf(-(gi0 + gh0)));
                float zg = 1.f / (1.f + expf(-(gi1 + gh1)));
                float n  = tanhf(gi2 + r * gh2);
                s.hn[tid] = (1.f - zg) * n + zg * hold;
            }
            __syncthreads();
        }

        // logits (per-wave shfl, from s.hn) + softmax + ALPHA + mix + h<-hn
        {
            const int lane = tid & 63;
            const int g = lane >> 3;
            const int cb = (lane & 7) * 16;
            f4 a4 = {0.f,0.f,0.f,0.f};
            #pragma unroll
            for (int q = 0; q < 4; ++q)
                a4 += *(const f4*)(W_out + (size_t)g*HG + cb + q*4) * *(const f4*)&s.hn[cb + q*4];
            float acc = a4[0]+a4[1]+a4[2]+a4[3];
            acc += __shfl_xor(acc, 1); acc += __shfl_xor(acc, 2); acc += __shfl_xor(acc, 4);
            float lg[8];
            #pragma unroll
            for (int k = 0; k < 8; ++k) lg[k] = __shfl(acc, k*8) + b_out[k];
            float mx = lg[0];
            #pragma unroll
            for (int k = 1; k < 8; ++k) mx = fmaxf(mx, lg[k]);
            float al[8]; float sum = 0.f;
            #pragma unroll
            for (int k = 0; k < 8; ++k) { al[k] = expf(lg[k] - mx); sum += al[k]; }
            float rs = 1.f / sum;
            #pragma unroll
            for (int k = 0; k < 8; ++k) al[k] *= rs;
            if (tid < 8) out[O_ALPHA + bt*8 + tid] = al[tid];
            mix_apply<true>(s, tid, bt, al, A_mats, B_mats, C_mats, out);
        }
        if (tid < HG) s.h[tid] = s.hn[tid];
        __syncthreads();

        // ---- P7: z_pred (via new AT + u(t)) ; Wk = A_new @ P_filt ----
        if (tid < 64) {
            float acc = 0.f;
            #pragma unroll 8
            for (int k = 0; k < DZc; ++k) acc += s.AT[k][tid] * s.z[k];
            #pragma unroll
            for (int q = 0; q < DUc; ++q) acc += s.Bm[tid][q] * s.ubuf[cur][q];
            s.zp[tid] = acc;
            out[O_ZPRED + bt*DZc + tid] = acc;
        }
        {
            f4 acc[4] = {{0.f,0.f,0.f,0.f},{0.f,0.f,0.f,0.f},{0.f,0.f,0.f,0.f},{0.f,0.f,0.f,0.f}};
            #pragma unroll 2
            for (int k4 = 0; k4 < 16; ++k4) {
                f4 ar0 = *(const f4*)&s.A[r4+0][k4*4];
                f4 ar1 = *(const f4*)&s.A[r4+1][k4*4];
                f4 ar2 = *(const f4*)&s.A[r4+2][k4*4];
                f4 ar3 = *(const f4*)&s.A[r4+3][k4*4];
                #pragma unroll
                for (int kk = 0; kk < 4; ++kk) {
                    f4 bv = *(const f4*)&s.P[k4*4+kk][c4];
                    acc[0] += ar0[kk] * bv; acc[1] += ar1[kk] * bv;
                    acc[2] += ar2[kk] * bv; acc[3] += ar3[kk] * bv;
                }
            }
            #pragma unroll
            for (int i = 0; i < 4; ++i)
                *(f4*)&s.Wk[r4+i][c4] = acc[i];
        }
        __syncthreads();

        // ---- P8: P_pred = Wk @ A^T + Q -> P + emit ; a_pred ; prefetch stores ----
        {
            f4 acc[4] = {{0.f,0.f,0.f,0.f},{0.f,0.f,0.f,0.f},{0.f,0.f,0.f,0.f},{0.f,0.f,0.f,0.f}};
            #pragma unroll 2
            for (int k4 = 0; k4 < 16; ++k4) {
                f4 w0 = *(const f4*)&s.Wk[r4+0][k4*4];
                f4 w1 = *(const f4*)&s.Wk[r4+1][k4*4];
                f4 w2 = *(const f4*)&s.Wk[r4+2][k4*4];
                f4 w3 = *(const f4*)&s.Wk[r4+3][k4*4];
                #pragma unroll
                for (int kk = 0; kk < 4; ++kk) {
                    f4 av = *(const f4*)&s.AT[k4*4+kk][c4];
                    acc[0] += w0[kk] * av; acc[1] += w1[kk] * av;
                    acc[2] += w2[kk] * av; acc[3] += w3[kk] * av;
                }
            }
            #pragma unroll
            for (int i = 0; i < 4; ++i) {
                const int row = r4 + i;
                f4 q = *(const f4*)&s.Qm[row][c4];
                f4 v = acc[i] + q;
                *(f4*)&s.P[row][c4] = v;
                *(f4*)&out[O_PPRED + bt*4096 + (size_t)row*64 + c4] = v;
            }
        }
        if (tid < DAc) {
            float acc = 0.f;
            #pragma unroll 4
            for (int k4 = 0; k4 < 16; ++k4)
                acc += dot4(*(const f4*)&s.C[tid][k4*4], *(const f4*)&s.zp[k4*4]);
            out[O_APRED + bt*DAc + tid] = acc;
        }
        // publish prefetched inputs for step t+1
        if (tid >= 192 && tid < 224)      s.akN[tid-192] = pfA;
        else if (tid >= 224 && tid < 232) s.ubuf[(t+1)&1][tid-224] = pfU;
        else if (tid == 232)              s.mkN = pfM;
        __syncthreads();
    }
}

// ---- kernel 2: batched 64x64 Cholesky, lane-per-row in LDS, stride 65 ----
__global__ void __launch_bounds__(64)
chol_batch(float* __restrict__ out)
{
    __shared__ float M[DZc][65];
    __shared__ float sd[DZc];
    const size_t bt = blockIdx.x;
    const int lane = threadIdx.x;
    const float* src = out + O_PFILT + bt*4096;
    #pragma unroll 4
    for (int e = 0; e < 16; ++e) {
        int i4 = lane + e*64;
        f4 v = *(const f4*)(src + (size_t)i4*4);
        int row = i4 >> 4, cb = (i4 & 15) * 4;
        M[row][cb] = v[0]; M[row][cb+1] = v[1]; M[row][cb+2] = v[2]; M[row][cb+3] = v[3];
    }
    __syncthreads();
    M[lane][lane] += 2.0e-4f;   // + 2*JITTER
    __syncthreads();
    for (int k = 0; k < DZc; ++k) {
        __threadfence_block();
        float mkk = M[k][k];
        if (lane == k) sd[k] = sqrtf(mkk);
        if (lane > k) {
            float f = M[lane][k] / mkk;
            for (int j = k + 1; j <= lane; ++j)
                M[lane][j] -= f * M[j][k];
        }
    }
    __threadfence_block();
    for (int k = 0; k < lane; ++k) M[lane][k] /= sd[k];
    M[lane][lane] = sd[lane];
    for (int k = lane + 1; k < DZc; ++k) M[lane][k] = 0.f;
    __syncthreads();
    float* dst = out + O_LTRIL + bt*4096;
    #pragma unroll 4
    for (int e = 0; e < 16; ++e) {
        int i4 = lane + e*64;
        int row = i4 >> 4, cb = (i4 & 15) * 4;
        f4 v = {M[row][cb], M[row][cb+1], M[row][cb+2], M[row][cb+3]};
        *(f4*)(dst + (size_t)i4*4) = v;
    }
}

extern "C" void kernel_launch(void* const* d_in, const int* in_sizes, int n_in,
                              void* d_out, int out_size, void* d_ws, size_t ws_size,
                              hipStream_t stream) {
    const float* a_seq  = (const float*)d_in[0];
    const float* h_obs  = (const float*)d_in[1];
    const float* u_seq  = (const float*)d_in[2];
    const float* mask   = (const float*)d_in[3];
    const float* A_mats = (const float*)d_in[4];
    const float* B_mats = (const float*)d_in[5];
    const float* C_mats = (const float*)d_in[6];
    const float* a_0    = (const float*)d_in[7];
    const float* P_0    = (const float*)d_in[8];
    const float* Q      = (const float*)d_in[9];
    const float* R      = (const float*)d_in[10];
    const float* W_ih   = (const float*)d_in[11];
    const float* W_hh   = (const float*)d_in[12];
    const float* b_ih   = (const float*)d_in[13];
    const float* b_hh   = (const float*)d_in[14];
    const float* W_out  = (const float*)d_in[15];
    const float* b_out  = (const float*)d_in[16];
    float* out = (float*)d_out;

    kalman_seq<<<dim3(BB), dim3(NT), 0, stream>>>(a_seq, h_obs, u_seq, mask,
        A_mats, B_mats, C_mats, a_0, P_0, Q, R, W_ih, W_hh, b_ih, b_hh, W_out, b_out, out);
    chol_batch<<<dim3(BB*BT), dim3(64), 0, stream>>>(out);
}

// Round 15
// 6335.192 us; speedup vs baseline: 1.2867x; 1.2867x over previous
//
#include <hip/hip_runtime.h>

typedef float f4 __attribute__((ext_vector_type(4)));

#define NT 256
#define BB 128
#define BT 100
#define DZc 64
#define DAc 32
#define DUc 8
#define KMIX 8
#define DOBSc 16
#define HG 128
#define DINc 56   // DA + DOBS + DU

// flat element offsets into d_out (return order of the reference tuple)
#define O_ZFILT   0LL
#define O_PFILT   819200LL
#define O_ZPRED   53248000LL
#define O_AFILT   54067200LL
#define O_APRED   54476800LL
#define O_PPRED   54886400LL
#define O_ALPHA   107315200LL
#define O_ASEQ    107417600LL
#define O_BSEQ    159846400LL
#define O_CSEQ    166400000LL
#define O_ZMEAN   192614400LL
#define O_LTRIL   193433600LL
#define O_SPRED   245862400LL

__device__ __forceinline__ float dot4(f4 a, f4 b) {
    return a[0]*b[0] + a[1]*b[1] + a[2]*b[2] + a[3]*b[3];
}

struct SMem {
    float P[DZc][68];     // covariance carry (P_pred -> P_filt -> P_pred)
    float A[DZc][68];     // mixed A (row-major)
    float AT[DZc][65];    // A transposed (2-way write pattern, free)
    float Wk[DZc][68];    // temp: A @ P_filt
    float Qm[DZc][68];    // Q cached
    float C[DAc][68];     // mixed C
    float CP[DAc][68];    // C@P
    float Xm[DAc][68];    // X = S^{-1} C P
    float S[DAc][33];     // innovation cov -> L (raw cols) after reg-LDL writeback
    float Rm[DAc][33];    // R cached
    float dinv[DAc];
    float col[64];        // pivot-column broadcast buffer for reg-LDL
    float Bm[DZc][8];     // mixed B
    float z[DZc], zp[DZc], zn[DZc];
    float h[HG], hn[HG];
    float gh[3*HG], gi[3*HG];   // only used by init + !mk1 slow path
    float x[64];          // [a_k_hat(32) | h_obs(16) | u(8)]
    float ak[DAc], rvec[DAc];
    float akN[DAc];       // prefetched a(t+1)
    float ubuf[2][8];     // u double-buffer: ubuf[t&1] = u(t)
    float mkN;            // prefetched mask(t+1)
    float lg[8];
    float mk;
};

template<bool EMIT>
__device__ __forceinline__ void mix_apply(SMem& s, int tid, size_t bt, const float* al8,
    const float* __restrict__ A_mats, const float* __restrict__ B_mats,
    const float* __restrict__ C_mats, float* __restrict__ out)
{
    const f4* A4 = (const f4*)A_mats;
    const f4* B4 = (const f4*)B_mats;
    const f4* C4 = (const f4*)C_mats;
    #pragma unroll 2
    for (int e = 0; e < 4; ++e) {
        int i4 = tid + e*256;
        f4 acc = {0.f,0.f,0.f,0.f};
        #pragma unroll
        for (int k = 0; k < 8; ++k) acc += al8[k] * A4[k*1024 + i4];
        int row = i4 >> 4, cb = (i4 & 15) * 4;
        *(f4*)&s.A[row][cb] = acc;
        s.AT[cb][row] = acc[0]; s.AT[cb+1][row] = acc[1];
        s.AT[cb+2][row] = acc[2]; s.AT[cb+3][row] = acc[3];
        if (EMIT) *(f4*)&out[O_ASEQ + bt*4096 + (size_t)i4*4] = acc;
    }
    if (tid < 128) {
        int i4 = tid;
        f4 acc = {0.f,0.f,0.f,0.f};
        #pragma unroll
        for (int k = 0; k < 8; ++k) acc += al8[k] * B4[k*128 + i4];
        *(f4*)&s.Bm[i4>>1][(i4&1)*4] = acc;
        if (EMIT) *(f4*)&out[O_BSEQ + bt*512 + (size_t)i4*4] = acc;
    }
    #pragma unroll 1
    for (int e = 0; e < 2; ++e) {
        int i4 = tid + e*256;
        f4 acc = {0.f,0.f,0.f,0.f};
        #pragma unroll
        for (int k = 0; k < 8; ++k) acc += al8[k] * C4[k*512 + i4];
        *(f4*)&s.C[i4>>4][(i4&15)*4] = acc;
    }
}

__global__ void __launch_bounds__(NT, 1)
kalman_seq(const float* __restrict__ a_seq, const float* __restrict__ h_obs,
           const float* __restrict__ u_seq, const float* __restrict__ mask,
           const float* __restrict__ A_mats, const float* __restrict__ B_mats,
           const float* __restrict__ C_mats, const float* __restrict__ a_0,
           const float* __restrict__ P_0, const float* __restrict__ Q,
           const float* __restrict__ R, const float* __restrict__ W_ih,
           const float* __restrict__ W_hh, const float* __restrict__ b_ih,
           const float* __restrict__ b_hh, const float* __restrict__ W_out,
           const float* __restrict__ b_out, float* __restrict__ out)
{
    __shared__ SMem s;
    const int b = blockIdx.x;
    const int tid = threadIdx.x;
    const int r4 = (tid >> 4) << 2;   // 4-row base
    const int c4 = (tid & 15) << 2;   // 4-col base

    // ---------------- init ----------------
    for (int idx = tid; idx < DZc*DZc; idx += NT) {
        s.P[idx >> 6][idx & 63]  = P_0[idx];
        s.Qm[idx >> 6][idx & 63] = Q[idx];
    }
    for (int idx = tid; idx < DAc*DAc; idx += NT) s.Rm[idx >> 5][idx & 31] = R[idx];
    if (tid < HG) s.h[tid] = 0.f;
    if (tid < DZc) { s.z[tid] = 0.f; s.zp[tid] = 0.f; }
    if (tid < DAc)                 s.x[tid] = a_0[tid];
    else if (tid < DAc + DOBSc)    s.x[tid] = h_obs[b*DOBSc + (tid - DAc)];
    else if (tid < DINc)           s.x[tid] = u_seq[(size_t)b*BT*DUc + (tid - DAc - DOBSc)];
    // prefill step-0 "prefetched" inputs
    if (tid >= 128 && tid < 160)      s.akN[tid-128] = a_seq[(size_t)b*BT*DAc + (tid-128)];
    else if (tid >= 160 && tid < 168) { s.ubuf[0][tid-160] = u_seq[(size_t)b*BT*DUc + (tid-160)];
                                        s.ubuf[1][tid-160] = 0.f; }
    else if (tid == 168)              s.mkN = mask[(size_t)b*BT];
    __syncthreads();

    // init alpha_net (h = 0 -> gh = b_hh exactly)
    for (int g = tid; g < 3*HG; g += NT) {
        const float* wi = W_ih + (size_t)g * DINc;
        f4 ai = {0.f,0.f,0.f,0.f};
        #pragma unroll 7
        for (int q = 0; q < 14; ++q) ai += *(const f4*)(wi + q*4) * *(const f4*)&s.x[q*4];
        s.gi[g] = ai[0]+ai[1]+ai[2]+ai[3] + b_ih[g];
        s.gh[g] = b_hh[g];
    }
    __syncthreads();
    if (tid < HG) {
        float r  = 1.f / (1.f + expf(-(s.gi[tid] + s.gh[tid])));
        float zg = 1.f / (1.f + expf(-(s.gi[HG+tid] + s.gh[HG+tid])));
        float n  = tanhf(s.gi[2*HG+tid] + r * s.gh[2*HG+tid]);
        s.h[tid] = (1.f - zg) * n;    // h_old = 0
    }
    __syncthreads();
    if (tid < KMIX) {
        const float* wo = W_out + tid * HG;
        f4 acc = {0.f,0.f,0.f,0.f};
        #pragma unroll 8
        for (int q = 0; q < 32; ++q) acc += *(const f4*)(wo + q*4) * *(const f4*)&s.h[q*4];
        s.lg[tid] = acc[0]+acc[1]+acc[2]+acc[3] + b_out[tid];
    }
    __syncthreads();
    {
        float lg[8];
        #pragma unroll
        for (int k = 0; k < 8; ++k) lg[k] = s.lg[k];
        float mx = lg[0];
        #pragma unroll
        for (int k = 1; k < 8; ++k) mx = fmaxf(mx, lg[k]);
        float al[8]; float sum = 0.f;
        #pragma unroll
        for (int k = 0; k < 8; ++k) { al[k] = expf(lg[k] - mx); sum += al[k]; }
        float rs = 1.f / sum;
        #pragma unroll
        for (int k = 0; k < 8; ++k) al[k] *= rs;
        mix_apply<false>(s, tid, 0, al, A_mats, B_mats, C_mats, out);
    }
    __syncthreads();

    for (int t = 0; t < BT; ++t) {
        const size_t bt = (size_t)b * BT + t;
        const int cur = t & 1;

        // ---- P0 (cheap): zp += B (u_new - u_old) ; publish prefetched inputs ----
        if (tid < 64) {
            float acc = s.zp[tid];
            #pragma unroll
            for (int q = 0; q < DUc; ++q)
                acc += s.Bm[tid][q] * (s.ubuf[cur][q] - s.ubuf[cur^1][q]);
            s.zp[tid] = acc;
        } else if (tid < 96) {
            float av = s.akN[tid-64];
            s.ak[tid-64] = av;
            s.x[tid-64] = av;                 // speculative a_k_hat (exact when mk==1)
        } else if (tid < 104) {
            s.x[48 + (tid-96)] = s.ubuf[cur][tid-96];
        } else if (tid == 104) {
            s.mk = s.mkN;
        }
        __syncthreads();
        const float mkv = s.mk;
        const bool mk1 = (mkv == 1.0f);

        // ---- P1: CP = C @ P (1 row x 8 cols per thread) ; rvec ----
        {
            const int r = tid >> 3;
            const int c8 = (tid & 7) * 8;
            f4 acc0 = {0.f,0.f,0.f,0.f}, acc1 = {0.f,0.f,0.f,0.f};
            #pragma unroll 4
            for (int k4 = 0; k4 < 16; ++k4) {
                f4 cr = *(const f4*)&s.C[r][k4*4];
                #pragma unroll
                for (int kk = 0; kk < 4; ++kk) {
                    float cv = cr[kk];
                    acc0 += cv * *(const f4*)&s.P[k4*4+kk][c8];
                    acc1 += cv * *(const f4*)&s.P[k4*4+kk][c8+4];
                }
            }
            *(f4*)&s.CP[r][c8]   = acc0;
            *(f4*)&s.CP[r][c8+4] = acc1;
        }
        if (tid < DAc) {
            float acc = 0.f;
            #pragma unroll 4
            for (int k4 = 0; k4 < 16; ++k4)
                acc += dot4(*(const f4*)&s.C[tid][k4*4], *(const f4*)&s.zp[k4*4]);
            s.rvec[tid] = s.ak[tid] - acc;
        }
        __syncthreads();

        // ---- P2: S = CP C^T + R (1x4 tiles) ; coalesced f4 emit ----
        {
            const int r = tid >> 3;
            const int cb = (tid & 7) * 4;
            f4 acc = {0.f,0.f,0.f,0.f};
            #pragma unroll 4
            for (int k4 = 0; k4 < 16; ++k4) {
                f4 a = *(const f4*)&s.CP[r][k4*4];
                #pragma unroll
                for (int j = 0; j < 4; ++j)
                    acc[j] += dot4(a, *(const f4*)&s.C[cb+j][k4*4]);
            }
            f4 rm = {s.Rm[r][cb], s.Rm[r][cb+1], s.Rm[r][cb+2], s.Rm[r][cb+3]};
            f4 v = acc + rm;
            s.S[r][cb] = v[0]; s.S[r][cb+1] = v[1]; s.S[r][cb+2] = v[2]; s.S[r][cb+3] = v[3];
            *(f4*)&out[O_SPRED + bt*1024 + (size_t)r*32 + cb] = v;
        }
        __syncthreads();

        // ---- P3: wave0: REGISTER LDL^T (pivot col via LDS broadcast) + reg solves
        //          waves1-2: GRU gates fully in-register -> s.hn
        //          wave3: C_seq emit ----
        if (tid < 64) {
            const int lane = tid;
            const int l = lane & 31;
            float row[32];
            #pragma unroll
            for (int j = 0; j < 32; ++j) row[j] = s.S[l][j];
            #pragma unroll
            for (int k = 0; k < 32; ++k) {
                if (lane < 32) s.col[lane] = row[k];
                __threadfence_block();
                float cb[32];
                #pragma unroll
                for (int jv = 0; jv < 8; ++jv) {
                    if (jv*4 + 3 >= k) {
                        f4 cv = *(const f4*)&s.col[jv*4];
                        cb[jv*4] = cv[0]; cb[jv*4+1] = cv[1];
                        cb[jv*4+2] = cv[2]; cb[jv*4+3] = cv[3];
                    }
                }
                float dv = 1.0f / cb[k];
                if (lane == k) s.dinv[k] = dv;
                float fm = (l > k) ? (row[k] * dv) : 0.f;
                #pragma unroll
                for (int j = k+1; j < 32; ++j)
                    row[j] -= fm * cb[j];
                __threadfence_block();
            }
            if (lane < 32) {
                #pragma unroll
                for (int j = 0; j < 32; ++j) s.S[l][j] = row[j];
            }
            __threadfence_block();
            float v[32];
            #pragma unroll
            for (int r = 0; r < 32; ++r) v[r] = s.CP[r][lane];
            #pragma unroll
            for (int r = 0; r < 32; ++r) {
                float acc = v[r];
                #pragma unroll
                for (int k = 0; k < r; ++k) acc -= s.S[r][k] * v[k];
                v[r] = s.dinv[r] * acc;
            }
            #pragma unroll
            for (int r = 30; r >= 0; --r) {
                float acc = 0.f;
                #pragma unroll
                for (int k = r+1; k < 32; ++k) acc += s.S[k][r] * v[k];
                v[r] -= s.dinv[r] * acc;
            }
            float accz = 0.f;
            #pragma unroll
            for (int r = 0; r < 32; ++r) {
                s.Xm[r][lane] = v[r];
                accz += v[r] * s.rvec[r];
            }
            s.zn[lane] = s.zp[lane] + mkv * accz;
            __threadfence_block();
            if (lane < DAc) {
                float acc = 0.f;
                #pragma unroll 4
                for (int k4 = 0; k4 < 16; ++k4)
                    acc += dot4(*(const f4*)&s.C[lane][k4*4], *(const f4*)&s.zn[k4*4]);
                out[O_AFILT + bt*DAc + lane] = acc;
                if (!mk1) s.x[lane] = mkv * s.ak[lane] + (1.f - mkv) * acc;
            }
        } else if (tid < 192) {
            const int idx = tid - 64;                // 0..127
            const float* wir = W_ih + (size_t)idx * DINc;
            const float* wiz = W_ih + (size_t)(HG + idx) * DINc;
            const float* win = W_ih + (size_t)(2*HG + idx) * DINc;
            const float* whr = W_hh + (size_t)idx * HG;
            const float* whz = W_hh + (size_t)(HG + idx) * HG;
            const float* whn = W_hh + (size_t)(2*HG + idx) * HG;
            f4 air = {0.f,0.f,0.f,0.f}, aiz = {0.f,0.f,0.f,0.f}, ain = {0.f,0.f,0.f,0.f};
            #pragma unroll 4
            for (int q = 0; q < 14; ++q) {
                f4 xv = *(const f4*)&s.x[q*4];
                air += *(const f4*)(wir + q*4) * xv;
                aiz += *(const f4*)(wiz + q*4) * xv;
                ain += *(const f4*)(win + q*4) * xv;
            }
            f4 ahr = {0.f,0.f,0.f,0.f}, ahz = {0.f,0.f,0.f,0.f}, ahn = {0.f,0.f,0.f,0.f};
            #pragma unroll 4
            for (int q = 0; q < 32; ++q) {
                f4 hv = *(const f4*)&s.h[q*4];
                ahr += *(const f4*)(whr + q*4) * hv;
                ahz += *(const f4*)(whz + q*4) * hv;
                ahn += *(const f4*)(whn + q*4) * hv;
            }
            float gir = air[0]+air[1]+air[2]+air[3] + b_ih[idx];
            float giz = aiz[0]+aiz[1]+aiz[2]+aiz[3] + b_ih[HG + idx];
            float gin = ain[0]+ain[1]+ain[2]+ain[3] + b_ih[2*HG + idx];
            float ghr = ahr[0]+ahr[1]+ahr[2]+ahr[3] + b_hh[idx];
            float ghz = ahz[0]+ahz[1]+ahz[2]+ahz[3] + b_hh[HG + idx];
            float ghn = ahn[0]+ahn[1]+ahn[2]+ahn[3] + b_hh[2*HG + idx];
            float r  = 1.f / (1.f + expf(-(gir + ghr)));
            float zg = 1.f / (1.f + expf(-(giz + ghz)));
            float n  = tanhf(gin + r * ghn);
            s.hn[idx] = (1.f - zg) * n + zg * s.h[idx];
        } else {
            const int l = tid - 192;
            #pragma unroll 2
            for (int e = 0; e < 8; ++e) {
                int i4 = l + e*64;
                *(f4*)&out[O_CSEQ + bt*2048 + (size_t)i4*4] = *(const f4*)&s.C[i4>>4][(i4&15)*4];
            }
        }
        __syncthreads();

        // ---- prefetch next-step inputs (issue now, store at P8 end) ----
        float pfA = 0.f, pfU = 0.f, pfM = 0.f;
        {
            const int t2 = (t+1 < BT) ? (t+1) : t;
            const size_t bt2 = (size_t)b*BT + t2;
            if (tid >= 192 && tid < 224)      pfA = a_seq[bt2*DAc + (tid-192)];
            else if (tid >= 224 && tid < 232) pfU = u_seq[bt2*DUc + (tid-224)];
            else if (tid == 232)              pfM = mask[bt2];
        }

        // ---- P4: P_filt fused update + emits ; (slow path if !mk1) ;
        //          logits + softmax + mix + h<-hn ----
        {
            const float coef = (mkv*mkv - 2.f*mkv) * 0.5f;
            f4 acc0 = {0.f,0.f,0.f,0.f}, acc1 = {0.f,0.f,0.f,0.f};
            f4 acc2 = {0.f,0.f,0.f,0.f}, acc3 = {0.f,0.f,0.f,0.f};
            #pragma unroll 4
            for (int l = 0; l < DAc; ++l) {
                f4 cpc = *(const f4*)&s.CP[l][c4];
                f4 xc  = *(const f4*)&s.Xm[l][c4];
                f4 cpr = *(const f4*)&s.CP[l][r4];
                f4 xr  = *(const f4*)&s.Xm[l][r4];
                acc0 += xr[0]*cpc + cpr[0]*xc;
                acc1 += xr[1]*cpc + cpr[1]*xc;
                acc2 += xr[2]*cpc + cpr[2]*xc;
                acc3 += xr[3]*cpc + cpr[3]*xc;
            }
            #pragma unroll
            for (int i = 0; i < 4; ++i) {
                const int row = r4 + i;
                f4 g = (i==0) ? acc0 : (i==1) ? acc1 : (i==2) ? acc2 : acc3;
                f4 p = *(const f4*)&s.P[row][c4];
                f4 v = p + coef * g;
                *(f4*)&s.P[row][c4] = v;
                *(f4*)&out[O_PFILT + bt*4096 + (size_t)row*64 + c4] = v;
            }
        }
        if (tid < DZc) {
            float v = s.zn[tid];
            out[O_ZFILT + bt*DZc + tid] = v;
            out[O_ZMEAN + bt*DZc + tid] = v;
            s.z[tid] = v;
        }

        if (!mk1) {
            __syncthreads();
            for (int g = tid; g < 3*HG; g += NT) {
                const float* wi = W_ih + (size_t)g * DINc;
                const float* wh = W_hh + (size_t)g * HG;
                f4 ai = {0.f,0.f,0.f,0.f}, ah = {0.f,0.f,0.f,0.f};
                #pragma unroll 7
                for (int q = 0; q < 14; ++q) ai += *(const f4*)(wi + q*4) * *(const f4*)&s.x[q*4];
                #pragma unroll 8
                for (int q = 0; q < 32; ++q) ah += *(const f4*)(wh + q*4) * *(const f4*)&s.h[q*4];
                s.gi[g] = ai[0]+ai[1]+ai[2]+ai[3] + b_ih[g];
                s.gh[g] = ah[0]+ah[1]+ah[2]+ah[3] + b_hh[g];
            }
            __syncthreads();
            if (tid < HG) {
                float gi0 = s.gi[tid], gi1 = s.gi[HG+tid], gi2 = s.gi[2*HG+tid];
                float gh0 = s.gh[tid], gh1 = s.gh[HG+tid], gh2 = s.gh[2*HG+tid];
                float hold = s.h[tid];
                float r  = 1.f / (1.f + expf(-(gi0 + gh0)));
                float zg = 1.f / (1.f + expf(-(gi1 + gh1)));
                float n  = tanhf(gi2 + r * gh2);
                s.hn[tid] = (1.f - zg) * n + zg * hold;
            }
            __syncthreads();
        }

        // logits (per-wave shfl, from s.hn) + softmax + ALPHA + mix + h<-hn
        {
            const int lane = tid & 63;
            const int g = lane >> 3;
            const int cb = (lane & 7) * 16;
            f4 a4 = {0.f,0.f,0.f,0.f};
            #pragma unroll
            for (int q = 0; q < 4; ++q)
                a4 += *(const f4*)(W_out + (size_t)g*HG + cb + q*4) * *(const f4*)&s.hn[cb + q*4];
            float acc = a4[0]+a4[1]+a4[2]+a4[3];
            acc += __shfl_xor(acc, 1); acc += __shfl_xor(acc, 2); acc += __shfl_xor(acc, 4);
            float lg[8];
            #pragma unroll
            for (int k = 0; k < 8; ++k) lg[k] = __shfl(acc, k*8) + b_out[k];
            float mx = lg[0];
            #pragma unroll
            for (int k = 1; k < 8; ++k) mx = fmaxf(mx, lg[k]);
            float al[8]; float sum = 0.f;
            #pragma unroll
            for (int k = 0; k < 8; ++k) { al[k] = expf(lg[k] - mx); sum += al[k]; }
            float rs = 1.f / sum;
            #pragma unroll
            for (int k = 0; k < 8; ++k) al[k] *= rs;
            if (tid < 8) out[O_ALPHA + bt*8 + tid] = al[tid];
            mix_apply<true>(s, tid, bt, al, A_mats, B_mats, C_mats, out);
        }
        if (tid < HG) s.h[tid] = s.hn[tid];
        __syncthreads();

        // ---- P7: z_pred (via new AT + u(t)) ; Wk = A_new @ P_filt ----
        if (tid < 64) {
            float acc = 0.f;
            #pragma unroll 8
            for (int k = 0; k < DZc; ++k) acc += s.AT[k][tid] * s.z[k];
            #pragma unroll
            for (int q = 0; q < DUc; ++q) acc += s.Bm[tid][q] * s.ubuf[cur][q];
            s.zp[tid] = acc;
            out[O_ZPRED + bt*DZc + tid] = acc;
        }
        {
            f4 acc[4] = {{0.f,0.f,0.f,0.f},{0.f,0.f,0.f,0.f},{0.f,0.f,0.f,0.f},{0.f,0.f,0.f,0.f}};
            #pragma unroll 2
            for (int k4 = 0; k4 < 16; ++k4) {
                f4 ar0 = *(const f4*)&s.A[r4+0][k4*4];
                f4 ar1 = *(const f4*)&s.A[r4+1][k4*4];
                f4 ar2 = *(const f4*)&s.A[r4+2][k4*4];
                f4 ar3 = *(const f4*)&s.A[r4+3][k4*4];
                #pragma unroll
                for (int kk = 0; kk < 4; ++kk) {
                    f4 bv = *(const f4*)&s.P[k4*4+kk][c4];
                    acc[0] += ar0[kk] * bv; acc[1] += ar1[kk] * bv;
                    acc[2] += ar2[kk] * bv; acc[3] += ar3[kk] * bv;
                }
            }
            #pragma unroll
            for (int i = 0; i < 4; ++i)
                *(f4*)&s.Wk[r4+i][c4] = acc[i];
        }
        __syncthreads();

        // ---- P8: P_pred = Wk @ A^T + Q -> P + emit ; a_pred ; prefetch stores ----
        {
            f4 acc[4] = {{0.f,0.f,0.f,0.f},{0.f,0.f,0.f,0.f},{0.f,0.f,0.f,0.f},{0.f,0.f,0.f,0.f}};
            #pragma unroll 2
            for (int k4 = 0; k4 < 16; ++k4) {
                f4 w0 = *(const f4*)&s.Wk[r4+0][k4*4];
                f4 w1 = *(const f4*)&s.Wk[r4+1][k4*4];
                f4 w2 = *(const f4*)&s.Wk[r4+2][k4*4];
                f4 w3 = *(const f4*)&s.Wk[r4+3][k4*4];
                #pragma unroll
                for (int kk = 0; kk < 4; ++kk) {
                    f4 av = *(const f4*)&s.AT[k4*4+kk][c4];
                    acc[0] += w0[kk] * av; acc[1] += w1[kk] * av;
                    acc[2] += w2[kk] * av; acc[3] += w3[kk] * av;
                }
            }
            #pragma unroll
            for (int i = 0; i < 4; ++i) {
                const int row = r4 + i;
                f4 q = *(const f4*)&s.Qm[row][c4];
                f4 v = acc[i] + q;
                *(f4*)&s.P[row][c4] = v;
                *(f4*)&out[O_PPRED + bt*4096 + (size_t)row*64 + c4] = v;
            }
        }
        if (tid < DAc) {
            float acc = 0.f;
            #pragma unroll 4
            for (int k4 = 0; k4 < 16; ++k4)
                acc += dot4(*(const f4*)&s.C[tid][k4*4], *(const f4*)&s.zp[k4*4]);
            out[O_APRED + bt*DAc + tid] = acc;
        }
        // publish prefetched inputs for step t+1
        if (tid >= 192 && tid < 224)      s.akN[tid-192] = pfA;
        else if (tid >= 224 && tid < 232) s.ubuf[(t+1)&1][tid-224] = pfU;
        else if (tid == 232)              s.mkN = pfM;
        __syncthreads();
    }
}

// ---- kernel 2: batched 64x64 Cholesky, lane-per-row in LDS, stride 65 ----
__global__ void __launch_bounds__(64)
chol_batch(float* __restrict__ out)
{
    __shared__ float M[DZc][65];
    __shared__ float sd[DZc];
    const size_t bt = blockIdx.x;
    const int lane = threadIdx.x;
    const float* src = out + O_PFILT + bt*4096;
    #pragma unroll 4
    for (int e = 0; e < 16; ++e) {
        int i4 = lane + e*64;
        f4 v = *(const f4*)(src + (size_t)i4*4);
        int row = i4 >> 4, cb = (i4 & 15) * 4;
        M[row][cb] = v[0]; M[row][cb+1] = v[1]; M[row][cb+2] = v[2]; M[row][cb+3] = v[3];
    }
    __syncthreads();
    M[lane][lane] += 2.0e-4f;   // + 2*JITTER
    __syncthreads();
    for (int k = 0; k < DZc; ++k) {
        __threadfence_block();
        float mkk = M[k][k];
        if (lane == k) sd[k] = sqrtf(mkk);
        if (lane > k) {
            float f = M[lane][k] / mkk;
            for (int j = k + 1; j <= lane; ++j)
                M[lane][j] -= f * M[j][k];
        }
    }
    __threadfence_block();
    for (int k = 0; k < lane; ++k) M[lane][k] /= sd[k];
    M[lane][lane] = sd[lane];
    for (int k = lane + 1; k < DZc; ++k) M[lane][k] = 0.f;
    __syncthreads();
    float* dst = out + O_LTRIL + bt*4096;
    #pragma unroll 4
    for (int e = 0; e < 16; ++e) {
        int i4 = lane + e*64;
        int row = i4 >> 4, cb = (i4 & 15) * 4;
        f4 v = {M[row][cb], M[row][cb+1], M[row][cb+2], M[row][cb+3]};
        *(f4*)(dst + (size_t)i4*4) = v;
    }
}

extern "C" void kernel_launch(void* const* d_in, const int* in_sizes, int n_in,
                              void* d_out, int out_size, void* d_ws, size_t ws_size,
                              hipStream_t stream) {
    const float* a_seq  = (const float*)d_in[0];
    const float* h_obs  = (const float*)d_in[1];
    const float* u_seq  = (const float*)d_in[2];
    const float* mask   = (const float*)d_in[3];
    const float* A_mats = (const float*)d_in[4];
    const float* B_mats = (const float*)d_in[5];
    const float* C_mats = (const float*)d_in[6];
    const float* a_0    = (const float*)d_in[7];
    const float* P_0    = (const float*)d_in[8];
    const float* Q      = (const float*)d_in[9];
    const float* R      = (const float*)d_in[10];
    const float* W_ih   = (const float*)d_in[11];
    const float* W_hh   = (const float*)d_in[12];
    const float* b_ih   = (const float*)d_in[13];
    const float* b_hh   = (const float*)d_in[14];
    const float* W_out  = (const float*)d_in[15];
    const float* b_out  = (const float*)d_in[16];
    float* out = (float*)d_out;

    kalman_seq<<<dim3(BB), dim3(NT), 0, stream>>>(a_seq, h_obs, u_seq, mask,
        A_mats, B_mats, C_mats, a_0, P_0, Q, R, W_ih, W_hh, b_ih, b_hh, W_out, b_out, out);
    chol_batch<<<dim3(BB*BT), dim3(64), 0, stream>>>(out);
}

// Round 17
// 6328.344 us; speedup vs baseline: 1.2881x; 1.0011x over previous
//
#include <hip/hip_runtime.h>

typedef float f4 __attribute__((ext_vector_type(4)));

#define NT 256
#define BB 128
#define BT 100
#define DZc 64
#define DAc 32
#define DUc 8
#define KMIX 8
#define DOBSc 16
#define HG 128
#define DINc 56   // DA + DOBS + DU

// flat element offsets into d_out (return order of the reference tuple)
#define O_ZFILT   0LL
#define O_PFILT   819200LL
#define O_ZPRED   53248000LL
#define O_AFILT   54067200LL
#define O_APRED   54476800LL
#define O_PPRED   54886400LL
#define O_ALPHA   107315200LL
#define O_ASEQ    107417600LL
#define O_BSEQ    159846400LL
#define O_CSEQ    166400000LL
#define O_ZMEAN   192614400LL
#define O_LTRIL   193433600LL
#define O_SPRED   245862400LL

__device__ __forceinline__ float dot4(f4 a, f4 b) {
    return a[0]*b[0] + a[1]*b[1] + a[2]*b[2] + a[3]*b[3];
}

struct SMem {
    float P[DZc][68];     // covariance carry (P_pred -> P_filt -> P_pred)
    float A[DZc][68];     // mixed A (row-major)
    float AT[DZc][65];    // A transposed (2-way write pattern, free)
    float Wk[DZc][68];    // temp: A @ P_filt
    float Qm[DZc][68];    // Q cached
    float C[DAc][68];     // mixed C
    float CP[DAc][68];    // C@P
    float Xm[DAc][68];    // X = S^{-1} C P
    float S[DAc][33];     // innovation cov -> L (raw cols) after reg-LDL writeback
    float Rm[DAc][33];    // R cached
    float dinv[DAc];
    float col[2][64];     // double-buffered pivot column for reg-LDL (1 fence/iter)
    float Bm[DZc][8];     // mixed B
    float z[DZc], zp[DZc], zn[DZc];   // zn: z_filt in P3/P4, then z_pred(t) holder in P7/P8
    float h[HG], hn[HG];
    float gh[3*HG], gi[3*HG];   // only used by init + !mk1 slow path
    float x[64];          // [a_k_hat(32) | h_obs(16) | u(8)]
    float ak[DAc], rvec[DAc];
    float ubuf[2][8];     // u double-buffer: ubuf[t&1] = u(t)
    float lg[8];
    float mk;
};

template<bool EMIT>
__device__ __forceinline__ void mix_apply(SMem& s, int tid, size_t bt, const float* al8,
    const float* __restrict__ A_mats, const float* __restrict__ B_mats,
    const float* __restrict__ C_mats, float* __restrict__ out)
{
    const f4* A4 = (const f4*)A_mats;
    const f4* B4 = (const f4*)B_mats;
    const f4* C4 = (const f4*)C_mats;
    #pragma unroll 2
    for (int e = 0; e < 4; ++e) {
        int i4 = tid + e*256;
        f4 acc = {0.f,0.f,0.f,0.f};
        #pragma unroll
        for (int k = 0; k < 8; ++k) acc += al8[k] * A4[k*1024 + i4];
        int row = i4 >> 4, cb = (i4 & 15) * 4;
        *(f4*)&s.A[row][cb] = acc;
        s.AT[cb][row] = acc[0]; s.AT[cb+1][row] = acc[1];
        s.AT[cb+2][row] = acc[2]; s.AT[cb+3][row] = acc[3];
        if (EMIT) *(f4*)&out[O_ASEQ + bt*4096 + (size_t)i4*4] = acc;
    }
    if (tid < 128) {
        int i4 = tid;
        f4 acc = {0.f,0.f,0.f,0.f};
        #pragma unroll
        for (int k = 0; k < 8; ++k) acc += al8[k] * B4[k*128 + i4];
        *(f4*)&s.Bm[i4>>1][(i4&1)*4] = acc;
        if (EMIT) *(f4*)&out[O_BSEQ + bt*512 + (size_t)i4*4] = acc;
    }
    #pragma unroll 1
    for (int e = 0; e < 2; ++e) {
        int i4 = tid + e*256;
        f4 acc = {0.f,0.f,0.f,0.f};
        #pragma unroll
        for (int k = 0; k < 8; ++k) acc += al8[k] * C4[k*512 + i4];
        *(f4*)&s.C[i4>>4][(i4&15)*4] = acc;
    }
}

__global__ void __launch_bounds__(NT, 1)
kalman_seq(const float* __restrict__ a_seq, const float* __restrict__ h_obs,
           const float* __restrict__ u_seq, const float* __restrict__ mask,
           const float* __restrict__ A_mats, const float* __restrict__ B_mats,
           const float* __restrict__ C_mats, const float* __restrict__ a_0,
           const float* __restrict__ P_0, const float* __restrict__ Q,
           const float* __restrict__ R, const float* __restrict__ W_ih,
           const float* __restrict__ W_hh, const float* __restrict__ b_ih,
           const float* __restrict__ b_hh, const float* __restrict__ W_out,
           const float* __restrict__ b_out, float* __restrict__ out)
{
    __shared__ SMem s;
    const int b = blockIdx.x;
    const int tid = threadIdx.x;
    const int r4 = (tid >> 4) << 2;   // 4-row base
    const int c4 = (tid & 15) << 2;   // 4-col base

    // ---------------- init ----------------
    for (int idx = tid; idx < DZc*DZc; idx += NT) {
        s.P[idx >> 6][idx & 63]  = P_0[idx];
        s.Qm[idx >> 6][idx & 63] = Q[idx];
    }
    for (int idx = tid; idx < DAc*DAc; idx += NT) s.Rm[idx >> 5][idx & 31] = R[idx];
    if (tid < HG) s.h[tid] = 0.f;
    if (tid < DZc) s.z[tid] = 0.f;
    if (tid < DAc)                 s.x[tid] = a_0[tid];
    else if (tid < DAc + DOBSc)    s.x[tid] = h_obs[b*DOBSc + (tid - DAc)];
    else if (tid < DINc)           s.x[tid] = u_seq[(size_t)b*BT*DUc + (tid - DAc - DOBSc)];
    if (tid >= 160 && tid < 168)   s.ubuf[0][tid-160] = u_seq[(size_t)b*BT*DUc + (tid-160)];
    __syncthreads();

    // init alpha_net (h = 0 -> gh = b_hh exactly), using x = [a_0 | h_obs | u(0)]
    for (int g = tid; g < 3*HG; g += NT) {
        const float* wi = W_ih + (size_t)g * DINc;
        f4 ai = {0.f,0.f,0.f,0.f};
        #pragma unroll 7
        for (int q = 0; q < 14; ++q) ai += *(const f4*)(wi + q*4) * *(const f4*)&s.x[q*4];
        s.gi[g] = ai[0]+ai[1]+ai[2]+ai[3] + b_ih[g];
        s.gh[g] = b_hh[g];
    }
    __syncthreads();
    if (tid < HG) {
        float r  = 1.f / (1.f + expf(-(s.gi[tid] + s.gh[tid])));
        float zg = 1.f / (1.f + expf(-(s.gi[HG+tid] + s.gh[HG+tid])));
        float n  = tanhf(s.gi[2*HG+tid] + r * s.gh[2*HG+tid]);
        s.h[tid] = (1.f - zg) * n;    // h_old = 0
    }
    __syncthreads();
    if (tid < KMIX) {
        const float* wo = W_out + tid * HG;
        f4 acc = {0.f,0.f,0.f,0.f};
        #pragma unroll 8
        for (int q = 0; q < 32; ++q) acc += *(const f4*)(wo + q*4) * *(const f4*)&s.h[q*4];
        s.lg[tid] = acc[0]+acc[1]+acc[2]+acc[3] + b_out[tid];
    }
    __syncthreads();
    {
        float lg[8];
        #pragma unroll
        for (int k = 0; k < 8; ++k) lg[k] = s.lg[k];
        float mx = lg[0];
        #pragma unroll
        for (int k = 1; k < 8; ++k) mx = fmaxf(mx, lg[k]);
        float al[8]; float sum = 0.f;
        #pragma unroll
        for (int k = 0; k < 8; ++k) { al[k] = expf(lg[k] - mx); sum += al[k]; }
        float rs = 1.f / sum;
        #pragma unroll
        for (int k = 0; k < 8; ++k) al[k] *= rs;
        mix_apply<false>(s, tid, 0, al, A_mats, B_mats, C_mats, out);
    }
    __syncthreads();

    // seed step-0 state: zp(0) = B u(0) (z0 = 0) ; ak/x = a(0) ; mk(0)
    if (tid < 64) {
        float acc = 0.f;
        #pragma unroll
        for (int q = 0; q < DUc; ++q) acc += s.Bm[tid][q] * s.ubuf[0][q];
        s.zp[tid] = acc;
    } else if (tid < 96) {
        float av = a_seq[(size_t)b*BT*DAc + (tid-64)];
        s.ak[tid-64] = av;
        s.x[tid-64] = av;                 // speculative a_k_hat (exact when mk==1)
    } else if (tid == 104) {
        s.mk = mask[(size_t)b*BT];
    }
    __syncthreads();

    for (int t = 0; t < BT; ++t) {
        const size_t bt = (size_t)b * BT + t;
        const int cur = t & 1;
        const float mkv = s.mk;
        const bool mk1 = (mkv == 1.0f);

        // ---- P1: CP = C @ P (1 row x 8 cols per thread) ; rvec ----
        {
            const int r = tid >> 3;
            const int c8 = (tid & 7) * 8;
            f4 acc0 = {0.f,0.f,0.f,0.f}, acc1 = {0.f,0.f,0.f,0.f};
            #pragma unroll 4
            for (int k4 = 0; k4 < 16; ++k4) {
                f4 cr = *(const f4*)&s.C[r][k4*4];
                #pragma unroll
                for (int kk = 0; kk < 4; ++kk) {
                    float cv = cr[kk];
                    acc0 += cv * *(const f4*)&s.P[k4*4+kk][c8];
                    acc1 += cv * *(const f4*)&s.P[k4*4+kk][c8+4];
                }
            }
            *(f4*)&s.CP[r][c8]   = acc0;
            *(f4*)&s.CP[r][c8+4] = acc1;
        }
        if (tid < DAc) {
            float acc = 0.f;
            #pragma unroll 4
            for (int k4 = 0; k4 < 16; ++k4)
                acc += dot4(*(const f4*)&s.C[tid][k4*4], *(const f4*)&s.zp[k4*4]);
            s.rvec[tid] = s.ak[tid] - acc;
        }
        __syncthreads();

        // ---- P2: S = CP C^T + R (1x4 tiles) ; coalesced f4 emit ----
        {
            const int r = tid >> 3;
            const int cb = (tid & 7) * 4;
            f4 acc = {0.f,0.f,0.f,0.f};
            #pragma unroll 4
            for (int k4 = 0; k4 < 16; ++k4) {
                f4 a = *(const f4*)&s.CP[r][k4*4];
                #pragma unroll
                for (int j = 0; j < 4; ++j)
                    acc[j] += dot4(a, *(const f4*)&s.C[cb+j][k4*4]);
            }
            f4 rm = {s.Rm[r][cb], s.Rm[r][cb+1], s.Rm[r][cb+2], s.Rm[r][cb+3]};
            f4 v = acc + rm;
            s.S[r][cb] = v[0]; s.S[r][cb+1] = v[1]; s.S[r][cb+2] = v[2]; s.S[r][cb+3] = v[3];
            *(f4*)&out[O_SPRED + bt*1024 + (size_t)r*32 + cb] = v;
        }
        __syncthreads();

        // ---- P3: wave0: REGISTER LDL^T (double-buffered pivot col, 1 fence/iter)
        //                 + reg solves + zn + a_filt
        //          waves1-2: GRU gates fully in-register -> s.hn
        //          wave3: C_seq emit ----
        if (tid < 64) {
            const int lane = tid;
            const int l = lane & 31;
            float row[32];
            #pragma unroll
            for (int j = 0; j < 32; ++j) row[j] = s.S[l][j];
            #pragma unroll
            for (int k = 0; k < 32; ++k) {
                if (lane < 32) s.col[k & 1][lane] = row[k];
                __threadfence_block();
                float cb[32];
                #pragma unroll
                for (int jv = 0; jv < 8; ++jv) {
                    if (jv*4 + 3 >= k) {
                        f4 cv = *(const f4*)&s.col[k & 1][jv*4];
                        cb[jv*4] = cv[0]; cb[jv*4+1] = cv[1];
                        cb[jv*4+2] = cv[2]; cb[jv*4+3] = cv[3];
                    }
                }
                float dv = 1.0f / cb[k];
                if (lane == k) s.dinv[k] = dv;
                float fm = (l > k) ? (row[k] * dv) : 0.f;
                #pragma unroll
                for (int j = k+1; j < 32; ++j)
                    row[j] -= fm * cb[j];
            }
            if (lane < 32) {
                #pragma unroll
                for (int j = 0; j < 32; ++j) s.S[l][j] = row[j];
            }
            __threadfence_block();
            float v[32];
            #pragma unroll
            for (int r = 0; r < 32; ++r) v[r] = s.CP[r][lane];
            #pragma unroll
            for (int r = 0; r < 32; ++r) {
                float acc = v[r];
                #pragma unroll
                for (int k = 0; k < r; ++k) acc -= s.S[r][k] * v[k];
                v[r] = s.dinv[r] * acc;
            }
            #pragma unroll
            for (int r = 30; r >= 0; --r) {
                float acc = 0.f;
                #pragma unroll
                for (int k = r+1; k < 32; ++k) acc += s.S[k][r] * v[k];
                v[r] -= s.dinv[r] * acc;
            }
            float accz = 0.f;
            #pragma unroll
            for (int r = 0; r < 32; ++r) {
                s.Xm[r][lane] = v[r];
                accz += v[r] * s.rvec[r];
            }
            s.zn[lane] = s.zp[lane] + mkv * accz;
            __threadfence_block();
            if (lane < DAc) {
                float acc = 0.f;
                #pragma unroll 4
                for (int k4 = 0; k4 < 16; ++k4)
                    acc += dot4(*(const f4*)&s.C[lane][k4*4], *(const f4*)&s.zn[k4*4]);
                out[O_AFILT + bt*DAc + lane] = acc;
                if (!mk1) s.x[lane] = mkv * s.ak[lane] + (1.f - mkv) * acc;
            }
        } else if (tid < 192) {
            const int idx = tid - 64;                // 0..127
            const float* wir = W_ih + (size_t)idx * DINc;
            const float* wiz = W_ih + (size_t)(HG + idx) * DINc;
            const float* win = W_ih + (size_t)(2*HG + idx) * DINc;
            const float* whr = W_hh + (size_t)idx * HG;
            const float* whz = W_hh + (size_t)(HG + idx) * HG;
            const float* whn = W_hh + (size_t)(2*HG + idx) * HG;
            f4 air = {0.f,0.f,0.f,0.f}, aiz = {0.f,0.f,0.f,0.f}, ain = {0.f,0.f,0.f,0.f};
            #pragma unroll 4
            for (int q = 0; q < 14; ++q) {
                f4 xv = *(const f4*)&s.x[q*4];
                air += *(const f4*)(wir + q*4) * xv;
                aiz += *(const f4*)(wiz + q*4) * xv;
                ain += *(const f4*)(win + q*4) * xv;
            }
            f4 ahr = {0.f,0.f,0.f,0.f}, ahz = {0.f,0.f,0.f,0.f}, ahn = {0.f,0.f,0.f,0.f};
            #pragma unroll 4
            for (int q = 0; q < 32; ++q) {
                f4 hv = *(const f4*)&s.h[q*4];
                ahr += *(const f4*)(whr + q*4) * hv;
                ahz += *(const f4*)(whz + q*4) * hv;
                ahn += *(const f4*)(whn + q*4) * hv;
            }
            float gir = air[0]+air[1]+air[2]+air[3] + b_ih[idx];
            float giz = aiz[0]+aiz[1]+aiz[2]+aiz[3] + b_ih[HG + idx];
            float gin = ain[0]+ain[1]+ain[2]+ain[3] + b_ih[2*HG + idx];
            float ghr = ahr[0]+ahr[1]+ahr[2]+ahr[3] + b_hh[idx];
            float ghz = ahz[0]+ahz[1]+ahz[2]+ahz[3] + b_hh[HG + idx];
            float ghn = ahn[0]+ahn[1]+ahn[2]+ahn[3] + b_hh[2*HG + idx];
            float r  = 1.f / (1.f + expf(-(gir + ghr)));
            float zg = 1.f / (1.f + expf(-(giz + ghz)));
            float n  = tanhf(gin + r * ghn);
            s.hn[idx] = (1.f - zg) * n + zg * s.h[idx];
        } else {
            const int l = tid - 192;
            #pragma unroll 2
            for (int e = 0; e < 8; ++e) {
                int i4 = l + e*64;
                *(f4*)&out[O_CSEQ + bt*2048 + (size_t)i4*4] = *(const f4*)&s.C[i4>>4][(i4&15)*4];
            }
        }
        __syncthreads();

        // ---- prefetch next-step inputs (issue now; u published in P4, rest at P8) ----
        float pfA = 0.f, pfU = 0.f, pfM = 0.f;
        {
            const int t2 = (t+1 < BT) ? (t+1) : t;
            const size_t bt2 = (size_t)b*BT + t2;
            if (tid >= 192 && tid < 224)      pfA = a_seq[bt2*DAc + (tid-192)];
            else if (tid >= 224 && tid < 232) pfU = u_seq[bt2*DUc + (tid-224)];
            else if (tid == 232)              pfM = mask[bt2];
        }

        // ---- P4: P_filt fused update + emits ; publish u(t+1) ; (slow path if !mk1) ;
        //          logits + softmax + mix + h<-hn ----
        {
            const float coef = (mkv*mkv - 2.f*mkv) * 0.5f;
            f4 acc0 = {0.f,0.f,0.f,0.f}, acc1 = {0.f,0.f,0.f,0.f};
            f4 acc2 = {0.f,0.f,0.f,0.f}, acc3 = {0.f,0.f,0.f,0.f};
            #pragma unroll 4
            for (int l = 0; l < DAc; ++l) {
                f4 cpc = *(const f4*)&s.CP[l][c4];
                f4 xc  = *(const f4*)&s.Xm[l][c4];
                f4 cpr = *(const f4*)&s.CP[l][r4];
                f4 xr  = *(const f4*)&s.Xm[l][r4];
                acc0 += xr[0]*cpc + cpr[0]*xc;
                acc1 += xr[1]*cpc + cpr[1]*xc;
                acc2 += xr[2]*cpc + cpr[2]*xc;
                acc3 += xr[3]*cpc + cpr[3]*xc;
            }
            #pragma unroll
            for (int i = 0; i < 4; ++i) {
                const int row = r4 + i;
                f4 g = (i==0) ? acc0 : (i==1) ? acc1 : (i==2) ? acc2 : acc3;
                f4 p = *(const f4*)&s.P[row][c4];
                f4 v = p + coef * g;
                *(f4*)&s.P[row][c4] = v;
                *(f4*)&out[O_PFILT + bt*4096 + (size_t)row*64 + c4] = v;
            }
        }
        if (tid < DZc) {
            float v = s.zn[tid];
            out[O_ZFILT + bt*DZc + tid] = v;
            out[O_ZMEAN + bt*DZc + tid] = v;
            s.z[tid] = v;
        }
        if (tid >= 224 && tid < 232) s.ubuf[(t+1)&1][tid-224] = pfU;   // u(t+1) for P7

        if (!mk1) {
            __syncthreads();
            for (int g = tid; g < 3*HG; g += NT) {
                const float* wi = W_ih + (size_t)g * DINc;
                const float* wh = W_hh + (size_t)g * HG;
                f4 ai = {0.f,0.f,0.f,0.f}, ah = {0.f,0.f,0.f,0.f};
                #pragma unroll 7
                for (int q = 0; q < 14; ++q) ai += *(const f4*)(wi + q*4) * *(const f4*)&s.x[q*4];
                #pragma unroll 8
                for (int q = 0; q < 32; ++q) ah += *(const f4*)(wh + q*4) * *(const f4*)&s.h[q*4];
                s.gi[g] = ai[0]+ai[1]+ai[2]+ai[3] + b_ih[g];
                s.gh[g] = ah[0]+ah[1]+ah[2]+ah[3] + b_hh[g];
            }
            __syncthreads();
            if (tid < HG) {
                float gi0 = s.gi[tid], gi1 = s.gi[HG+tid], gi2 = s.gi[2*HG+tid];
                float gh0 = s.gh[tid], gh1 = s.gh[HG+tid], gh2 = s.gh[2*HG+tid];
                float hold = s.h[tid];
                float r  = 1.f / (1.f + expf(-(gi0 + gh0)));
                float zg = 1.f / (1.f + expf(-(gi1 + gh1)));
                float n  = tanhf(gi2 + r * gh2);
                s.hn[tid] = (1.f - zg) * n + zg * hold;
            }
            __syncthreads();
        }

        // logits (per-wave shfl, from s.hn) + softmax + ALPHA + mix + h<-hn
        {
            const int lane = tid & 63;
            const int g = lane >> 3;
            const int cb = (lane & 7) * 16;
            f4 a4 = {0.f,0.f,0.f,0.f};
            #pragma unroll
            for (int q = 0; q < 4; ++q)
                a4 += *(const f4*)(W_out + (size_t)g*HG + cb + q*4) * *(const f4*)&s.hn[cb + q*4];
            float acc = a4[0]+a4[1]+a4[2]+a4[3];
            acc += __shfl_xor(acc, 1); acc += __shfl_xor(acc, 2); acc += __shfl_xor(acc, 4);
            float lg[8];
            #pragma unroll
            for (int k = 0; k < 8; ++k) lg[k] = __shfl(acc, k*8) + b_out[k];
            float mx = lg[0];
            #pragma unroll
            for (int k = 1; k < 8; ++k) mx = fmaxf(mx, lg[k]);
            float al[8]; float sum = 0.f;
            #pragma unroll
            for (int k = 0; k < 8; ++k) { al[k] = expf(lg[k] - mx); sum += al[k]; }
            float rs = 1.f / sum;
            #pragma unroll
            for (int k = 0; k < 8; ++k) al[k] *= rs;
            if (tid < 8) out[O_ALPHA + bt*8 + tid] = al[tid];
            mix_apply<true>(s, tid, bt, al, A_mats, B_mats, C_mats, out);
        }
        if (tid < HG) s.h[tid] = s.hn[tid];
        __syncthreads();

        // ---- P7: z_pred(t) -> s.zn (emit) ; zp(t+1) -> s.zp ; Wk = A_new @ P_filt ----
        if (tid < 64) {
            float acc = 0.f;
            #pragma unroll 8
            for (int k = 0; k < DZc; ++k) acc += s.AT[k][tid] * s.z[k];
            #pragma unroll
            for (int q = 0; q < DUc; ++q) acc += s.Bm[tid][q] * s.ubuf[cur][q];
            out[O_ZPRED + bt*DZc + tid] = acc;
            s.zn[tid] = acc;                  // park z_pred(t) for P8's a_pred
            // zp(t+1) = z_pred(t) + B (u(t+1) - u(t))   [A,B unchanged until next mix]
            #pragma unroll
            for (int q = 0; q < DUc; ++q)
                acc += s.Bm[tid][q] * (s.ubuf[cur^1][q] - s.ubuf[cur][q]);
            s.zp[tid] = acc;
        }
        {
            f4 acc[4] = {{0.f,0.f,0.f,0.f},{0.f,0.f,0.f,0.f},{0.f,0.f,0.f,0.f},{0.f,0.f,0.f,0.f}};
            #pragma unroll 2
            for (int k4 = 0; k4 < 16; ++k4) {
                f4 ar0 = *(const f4*)&s.A[r4+0][k4*4];
                f4 ar1 = *(const f4*)&s.A[r4+1][k4*4];
                f4 ar2 = *(const f4*)&s.A[r4+2][k4*4];
                f4 ar3 = *(const f4*)&s.A[r4+3][k4*4];
                #pragma unroll
                for (int kk = 0; kk < 4; ++kk) {
                    f4 bv = *(const f4*)&s.P[k4*4+kk][c4];
                    acc[0] += ar0[kk] * bv; acc[1] += ar1[kk] * bv;
                    acc[2] += ar2[kk] * bv; acc[3] += ar3[kk] * bv;
                }
            }
            #pragma unroll
            for (int i = 0; i < 4; ++i)
                *(f4*)&s.Wk[r4+i][c4] = acc[i];
        }
        __syncthreads();

        // ---- P8: P_pred = Wk @ A^T + Q -> P + emit ; a_pred (from s.zn) ; publish next ----
        {
            f4 acc[4] = {{0.f,0.f,0.f,0.f},{0.f,0.f,0.f,0.f},{0.f,0.f,0.f,0.f},{0.f,0.f,0.f,0.f}};
            #pragma unroll 2
            for (int k4 = 0; k4 < 16; ++k4) {
                f4 w0 = *(const f4*)&s.Wk[r4+0][k4*4];
                f4 w1 = *(const f4*)&s.Wk[r4+1][k4*4];
                f4 w2 = *(const f4*)&s.Wk[r4+2][k4*4];
                f4 w3 = *(const f4*)&s.Wk[r4+3][k4*4];
                #pragma unroll
                for (int kk = 0; kk < 4; ++kk) {
                    f4 av = *(const f4*)&s.AT[k4*4+kk][c4];
                    acc[0] += w0[kk] * av; acc[1] += w1[kk] * av;
                    acc[2] += w2[kk] * av; acc[3] += w3[kk] * av;
                }
            }
            #pragma unroll
            for (int i = 0; i < 4; ++i) {
                const int row = r4 + i;
                f4 q = *(const f4*)&s.Qm[row][c4];
                f4 v = acc[i] + q;
                *(f4*)&s.P[row][c4] = v;
                *(f4*)&out[O_PPRED + bt*4096 + (size_t)row*64 + c4] = v;
            }
        }
        if (tid < DAc) {
            float acc = 0.f;
            #pragma unroll 4
            for (int k4 = 0; k4 < 16; ++k4)
                acc += dot4(*(const f4*)&s.C[tid][k4*4], *(const f4*)&s.zn[k4*4]);
            out[O_APRED + bt*DAc + tid] = acc;
        }
        // publish step-(t+1) inputs
        if (tid >= 192 && tid < 224) {
            s.ak[tid-192] = pfA;
            s.x[tid-192]  = pfA;              // speculative a_k_hat
        } else if (tid >= 224 && tid < 232) {
            s.x[48 + (tid-224)] = pfU;        // u(t+1) into GRU input
        } else if (tid == 232) {
            s.mk = pfM;
        }
        __syncthreads();
    }
}

// ---- kernel 2: batched 64x64 Cholesky, lane-per-row in LDS, stride 65 ----
__global__ void __launch_bounds__(64)
chol_batch(float* __restrict__ out)
{
    __shared__ float M[DZc][65];
    __shared__ float sd[DZc];
    const size_t bt = blockIdx.x;
    const int lane = threadIdx.x;
    const float* src = out + O_PFILT + bt*4096;
    #pragma unroll 4
    for (int e = 0; e < 16; ++e) {
        int i4 = lane + e*64;
        f4 v = *(const f4*)(src + (size_t)i4*4);
        int row = i4 >> 4, cb = (i4 & 15) * 4;
        M[row][cb] = v[0]; M[row][cb+1] = v[1]; M[row][cb+2] = v[2]; M[row][cb+3] = v[3];
    }
    __syncthreads();
    M[lane][lane] += 2.0e-4f;   // + 2*JITTER
    __syncthreads();
    for (int k = 0; k < DZc; ++k) {
        __threadfence_block();
        float mkk = M[k][k];
        if (lane == k) sd[k] = sqrtf(mkk);
        if (lane > k) {
            float f = M[lane][k] / mkk;
            for (int j = k + 1; j <= lane; ++j)
                M[lane][j] -= f * M[j][k];
        }
    }
    __threadfence_block();
    for (int k = 0; k < lane; ++k) M[lane][k] /= sd[k];
    M[lane][lane] = sd[lane];
    for (int k = lane + 1; k < DZc; ++k) M[lane][k] = 0.f;
    __syncthreads();
    float* dst = out + O_LTRIL + bt*4096;
    #pragma unroll 4
    for (int e = 0; e < 16; ++e) {
        int i4 = lane + e*64;
        int row = i4 >> 4, cb = (i4 & 15) * 4;
        f4 v = {M[row][cb], M[row][cb+1], M[row][cb+2], M[row][cb+3]};
        *(f4*)(dst + (size_t)i4*4) = v;
    }
}

extern "C" void kernel_launch(void* const* d_in, const int* in_sizes, int n_in,
                              void* d_out, int out_size, void* d_ws, size_t ws_size,
                              hipStream_t stream) {
    const float* a_seq  = (const float*)d_in[0];
    const float* h_obs  = (const float*)d_in[1];
    const float* u_seq  = (const float*)d_in[2];
    const float* mask   = (const float*)d_in[3];
    const float* A_mats = (const float*)d_in[4];
    const float* B_mats = (const float*)d_in[5];
    const float* C_mats = (const float*)d_in[6];
    const float* a_0    = (const float*)d_in[7];
    const float* P_0    = (const float*)d_in[8];
    const float* Q      = (const float*)d_in[9];
    const float* R      = (const float*)d_in[10];
    const float* W_ih   = (const float*)d_in[11];
    const float* W_hh   = (const float*)d_in[12];
    const float* b_ih   = (const float*)d_in[13];
    const float* b_hh   = (const float*)d_in[14];
    const float* W_out  = (const float*)d_in[15];
    const float* b_out  = (const float*)d_in[16];
    float* out = (float*)d_out;

    kalman_seq<<<dim3(BB), dim3(NT), 0, stream>>>(a_seq, h_obs, u_seq, mask,
        A_mats, B_mats, C_mats, a_0, P_0, Q, R, W_ih, W_hh, b_ih, b_hh, W_out, b_out, out);
    chol_batch<<<dim3(BB*BT), dim3(64), 0, stream>>>(out);
}